// Round 15
// baseline (8963.154 us; speedup 1.0000x reference)
//
#include <hip/hip_runtime.h>
#include <math.h>

#define HD 1024
#define CD 256
#define TT 512
#define GD 4096                 // 4*H
#define NWG 256
#define NTH 1024
#define WPB 16                  // waves per block
#define NMIR 8                  // mirror copies of published state (fan-out/8)
#define LAMF 0.05f
#define SMEMB (4 * WPB * HD * 2)   // 128 KB dynamic LDS: M2,W2b,Whh2,M3 rows

typedef unsigned long long ull;
typedef unsigned short ushortt;
typedef _Float16 hh2 __attribute__((ext_vector_type(2)));

// ---------------- fp16 weight copies (built per call) ---------------------
__device__ __align__(16) ushortt hM1[GD * CD];    //  2 MB : Wih1[:,:H]@Ww0
__device__ __align__(16) ushortt hM2[GD * HD];    //  8 MB : Wih2[:,:H]@Ww1
__device__ __align__(16) ushortt hM3[GD * HD];    //  8 MB : Wih3@Ww2
__device__ __align__(16) ushortt hW1b[GD * HD];   //  8 MB : Wih1[:,H:]
__device__ __align__(16) ushortt hWhh1[GD * HD];  //  8 MB
__device__ __align__(16) ushortt hW2b[GD * HD];   //  8 MB : Wih2[:,H:]
__device__ __align__(16) ushortt hWhh2[GD * HD];  //  8 MB
__device__ __align__(16) ushortt hWhh3[GD * HD];  //  8 MB
__device__ __align__(16) ushortt hVw1[CD * HD];   // .5 MB
__device__ __align__(16) ushortt hVw2[HD * HD];   //  2 MB
__device__ __align__(16) ushortt hVw3[HD * HD];   //  2 MB

// ---------------- published cross-WG state, mirrored NMIR x ----------------
__device__ __align__(8) ushortt d_h1m[NMIR][HD], d_TD1m[NMIR][HD], d_h3m[NMIR][HD];
__device__ __align__(8) ushortt d_h2m[NMIR][HD], d_TD2m[NMIR][HD];
__device__ __align__(16) float d_z1m[NMIR][CD];
// two-hop distributed barrier: per-WG flag line + NMIR mirrored release lines
__device__ int d_arr[NWG][32];
__device__ int d_relm[NMIR][32];

__global__ void pc_init() {
  d_arr[threadIdx.x][0] = 0;
  if (threadIdx.x < NMIR) d_relm[threadIdx.x][0] = 0;
}

__device__ __forceinline__ float sigf(float x)     { return 1.f / (1.f + __expf(-x)); }
__device__ __forceinline__ float tanhfast(float x) { return 1.f - 2.f / (1.f + __expf(2.f * x)); }

__device__ __forceinline__ ushortt f2h(float x) {
  union { ushortt u; _Float16 h; } c; c.h = (_Float16)x; return c.u;
}
__device__ __forceinline__ float h2f(ushortt u) {
  union { ushortt u; _Float16 h; } c; c.u = u; return (float)c.h;
}
__device__ __forceinline__ unsigned packh2(float a, float b) {
  union { unsigned u; hh2 h; } c; c.h = hh2{(_Float16)a, (_Float16)b}; return c.u;
}
__device__ __forceinline__ float fd2(unsigned a, unsigned b, float c) {
  union { unsigned u; hh2 h; } ua, ub; ua.u = a; ub.u = b;
  return __builtin_amdgcn_fdot2(ua.h, ub.h, c, false);
}

__device__ __forceinline__ float cload(const float* p) {
  return __hip_atomic_load(p, __ATOMIC_RELAXED, __HIP_MEMORY_SCOPE_AGENT);
}
__device__ __forceinline__ void cstore(float* p, float v) {
  __hip_atomic_store(p, v, __ATOMIC_RELAXED, __HIP_MEMORY_SCOPE_AGENT);
}
__device__ __forceinline__ float2 cload2(const float* p) {
  union { ull u; float2 f; } c;
  c.u = __hip_atomic_load((const ull*)p, __ATOMIC_RELAXED, __HIP_MEMORY_SCOPE_AGENT);
  return c.f;
}
__device__ __forceinline__ uint2 cloadU2(const ushortt* p) {
  union { ull u; uint2 v; } c;
  c.u = __hip_atomic_load((const ull*)p, __ATOMIC_RELAXED, __HIP_MEMORY_SCOPE_AGENT);
  return c.v;
}
__device__ __forceinline__ void cstoreU2(ushortt* p, uint2 v) {
  union { ull u; uint2 v; } c; c.v = v;
  __hip_atomic_store((ull*)p, c.u, __ATOMIC_RELAXED, __HIP_MEMORY_SCOPE_AGENT);
}

// Split two-hop barrier: arrive early (right after publish), wait late
// (after the precompute dots). The precompute then overlaps the gather
// window instead of delaying this WG's arrival.
__device__ __forceinline__ void garrive(int& ep) {
  ++ep;
  __syncthreads();               // all waves' publishes done
  if (blockIdx.x != 0 && threadIdx.x == 0)
    __hip_atomic_store(&d_arr[blockIdx.x][0], ep, __ATOMIC_RELEASE, __HIP_MEMORY_SCOPE_AGENT);
}
__device__ __forceinline__ void gwait(int ep) {
  const int tid = threadIdx.x;
  if (blockIdx.x == 0) {
    if (tid >= 1 && tid < NWG) {
      while (__hip_atomic_load(&d_arr[tid][0], __ATOMIC_RELAXED, __HIP_MEMORY_SCOPE_AGENT) < ep)
        __builtin_amdgcn_s_sleep(1);
    }
    __syncthreads();
    if (tid < NMIR)              // RELEASE drains WG0's own publishes too
      __hip_atomic_store(&d_relm[tid][0], ep, __ATOMIC_RELEASE, __HIP_MEMORY_SCOPE_AGENT);
    __syncthreads();
  } else {
    if (tid == 0) {
      while (__hip_atomic_load(&d_relm[blockIdx.x & (NMIR - 1)][0],
                               __ATOMIC_RELAXED, __HIP_MEMORY_SCOPE_AGENT) < ep)
        __builtin_amdgcn_s_sleep(1);
    }
    __syncthreads();
  }
}

__device__ __forceinline__ float wredsum(float v) {
  #pragma unroll
  for (int off = 32; off; off >>= 1) v += __shfl_xor(v, off);
  return v;
}
__device__ __forceinline__ float wredmax(float v) {
  #pragma unroll
  for (int off = 32; off; off >>= 1) v = fmaxf(v, __shfl_xor(v, off));
  return v;
}

// fp32 dot (prologue only)
__device__ __forceinline__ float dotp(const float* __restrict__ w, const float* xv, int n, int lane) {
  float a0 = 0.f, a1 = 0.f, a2 = 0.f, a3 = 0.f;
  for (int c = lane * 4; c < n; c += 256) {
    const float4 wv = *(const float4*)(w + c);
    const float4 vv = *(const float4*)(xv + c);
    a0 = fmaf(wv.x, vv.x, a0); a1 = fmaf(wv.y, vv.y, a1);
    a2 = fmaf(wv.z, vv.z, a2); a3 = fmaf(wv.w, vv.w, a3);
  }
  return (a0 + a1) + (a2 + a3);
}

// fp16 dot over 1024 halves (weight row pointer: global OR LDS)
__device__ __forceinline__ float dotH(const ushortt* __restrict__ w, const ushortt* xv, int lane) {
  const uint4 w0 = *(const uint4*)(w + lane * 8);
  const uint4 w1 = *(const uint4*)(w + lane * 8 + 512);
  const uint4 v0 = *(const uint4*)(xv + lane * 8);
  const uint4 v1 = *(const uint4*)(xv + lane * 8 + 512);
  float a = 0.f;
  a = fd2(w0.x, v0.x, a); a = fd2(w0.y, v0.y, a);
  a = fd2(w0.z, v0.z, a); a = fd2(w0.w, v0.w, a);
  a = fd2(w1.x, v1.x, a); a = fd2(w1.y, v1.y, a);
  a = fd2(w1.z, v1.z, a); a = fd2(w1.w, v1.w, a);
  return a;
}
// fp16 dot over 256 halves
__device__ __forceinline__ float dotH256(const ushortt* __restrict__ w, const ushortt* xv, int lane) {
  const uint2 wv = *(const uint2*)(w + lane * 4);
  const uint2 vv = *(const uint2*)(xv + lane * 4);
  float a = fd2(wv.x, vv.x, 0.f);
  return fd2(wv.y, vv.y, a);
}

// ---------------- fp32->fp16 weight conversion ----------------------------
__global__ __launch_bounds__(256) void pc_conv(
    const float* __restrict__ Wih1, const float* __restrict__ Whh1,
    const float* __restrict__ Wih2, const float* __restrict__ Whh2,
    const float* __restrict__ Whh3, const float* __restrict__ Vw1,
    const float* __restrict__ Vw2,  const float* __restrict__ Vw3) {
  const size_t stride = (size_t)gridDim.x * 256;
  const size_t i0 = (size_t)blockIdx.x * 256 + threadIdx.x;
  for (size_t i = i0; i < (size_t)GD * HD; i += stride) {
    size_t r = i >> 10, c = i & 1023;
    size_t src = (r << 11) + HD + c;
    hW1b[i]  = f2h(Wih1[src]);
    hW2b[i]  = f2h(Wih2[src]);
    hWhh1[i] = f2h(Whh1[i]);
    hWhh2[i] = f2h(Whh2[i]);
    hWhh3[i] = f2h(Whh3[i]);
  }
  for (size_t i = i0; i < (size_t)HD * HD; i += stride) {
    hVw2[i] = f2h(Vw2[i]);
    hVw3[i] = f2h(Vw3[i]);
  }
  for (size_t i = i0; i < (size_t)CD * HD; i += stride) hVw1[i] = f2h(Vw1[i]);
}

// ---------------- fold GEMM: fp16 C[4096 x N] = A @ B ---------------------
__global__ __launch_bounds__(256) void pc_fold(
    const float* __restrict__ Wih1, const float* __restrict__ Wih2,
    const float* __restrict__ Wih3, const float* __restrict__ Ww0,
    const float* __restrict__ Ww1,  const float* __restrict__ Ww2) {
  int b = blockIdx.x;
  const float* A; const float* B; ushortt* C; int N, lda;
  if (b < 256)        { A = Wih1; B = Ww0; C = hM1; N = CD; lda = 2 * HD; }
  else if (b < 1280)  { A = Wih2; B = Ww1; C = hM2; N = HD; lda = 2 * HD; b -= 256; }
  else                { A = Wih3; B = Ww2; C = hM3; N = HD; lda = HD;     b -= 1280; }
  const int ctiles = N >> 6;
  const int rt = b / ctiles, ct = b - rt * ctiles;
  const int tid = threadIdx.x;
  const int tx = tid & 15, ty = tid >> 4;

  __shared__ float sA[16][65];
  __shared__ float sB[16][64];

  float acc[4][4] = {};
  const int ar = tid >> 2, aq = tid & 3;
  const int br = tid >> 4, bq = tid & 15;

  for (int kk = 0; kk < HD; kk += 16) {
    float4 av = *(const float4*)(A + (size_t)(rt * 64 + ar) * lda + kk + aq * 4);
    float4 bv = *(const float4*)(B + (size_t)(kk + br) * N + ct * 64 + bq * 4);
    __syncthreads();
    sA[aq * 4 + 0][ar] = av.x; sA[aq * 4 + 1][ar] = av.y;
    sA[aq * 4 + 2][ar] = av.z; sA[aq * 4 + 3][ar] = av.w;
    *(float4*)&sB[br][bq * 4] = bv;
    __syncthreads();
    #pragma unroll
    for (int k = 0; k < 16; ++k) {
      const float4 b4 = *(const float4*)&sB[k][tx * 4];
      const float a0 = sA[k][ty * 4 + 0], a1 = sA[k][ty * 4 + 1];
      const float a2 = sA[k][ty * 4 + 2], a3 = sA[k][ty * 4 + 3];
      acc[0][0] = fmaf(a0, b4.x, acc[0][0]); acc[0][1] = fmaf(a0, b4.y, acc[0][1]);
      acc[0][2] = fmaf(a0, b4.z, acc[0][2]); acc[0][3] = fmaf(a0, b4.w, acc[0][3]);
      acc[1][0] = fmaf(a1, b4.x, acc[1][0]); acc[1][1] = fmaf(a1, b4.y, acc[1][1]);
      acc[1][2] = fmaf(a1, b4.z, acc[1][2]); acc[1][3] = fmaf(a1, b4.w, acc[1][3]);
      acc[2][0] = fmaf(a2, b4.x, acc[2][0]); acc[2][1] = fmaf(a2, b4.y, acc[2][1]);
      acc[2][2] = fmaf(a2, b4.z, acc[2][2]); acc[2][3] = fmaf(a2, b4.w, acc[2][3]);
      acc[3][0] = fmaf(a3, b4.x, acc[3][0]); acc[3][1] = fmaf(a3, b4.y, acc[3][1]);
      acc[3][2] = fmaf(a3, b4.z, acc[3][2]); acc[3][3] = fmaf(a3, b4.w, acc[3][3]);
    }
  }
  #pragma unroll
  for (int i = 0; i < 4; ++i) {
    uint2 r = make_uint2(packh2(acc[i][0], acc[i][1]), packh2(acc[i][2], acc[i][3]));
    *(uint2*)(C + (size_t)(rt * 64 + ty * 4 + i) * N + ct * 64 + tx * 4) = r;
  }
}

__global__ __launch_bounds__(NTH, 1) void pc_main(
    const float* __restrict__ x,
    const float* __restrict__ Wih1, const float* __restrict__ Whh1,
    const float* __restrict__ bih1, const float* __restrict__ bhh1,
    const float* __restrict__ Vw1,  const float* __restrict__ Vb1,
    const float* __restrict__ Wih2, const float* __restrict__ Whh2,
    const float* __restrict__ bih2, const float* __restrict__ bhh2,
    const float* __restrict__ Vw2,  const float* __restrict__ Vb2,
    const float* __restrict__ Wih3, const float* __restrict__ Whh3,
    const float* __restrict__ bih3, const float* __restrict__ bhh3,
    const float* __restrict__ Vw3,  const float* __restrict__ Vb3,
    const float* __restrict__ Ww0,  const float* __restrict__ Wb0,
    const float* __restrict__ Ww1,  const float* __restrict__ Wb1,
    const float* __restrict__ Ww2,  const float* __restrict__ Wb2,
    const float* __restrict__ r1,   const float* __restrict__ r2,
    const float* __restrict__ r3,
    float* __restrict__ out) {
  const int tid  = threadIdx.x;
  const int lane = tid & 63;
  const int bid  = blockIdx.x;
  const int wv   = tid >> 6;            // wave index within block
  const int gi   = wv & 3;              // gate index (i,f,g,o)
  const int slot = wv >> 2;             // owned-element slot 0..3
  const int rg   = gi * HD + bid * 4 + slot;   // this wave's gate row
  const int jown = bid * 4 + slot;      // element for rec/z rows
  const int mi   = bid & (NMIR - 1);    // this WG's mirror index
  const bool iswg0 = (bid == 0);
  const bool w0    = iswg0 && tid < 64;

  // dynamic LDS: per-wave private weight rows
  extern __shared__ __align__(16) ushortt smem[];
  ushortt* sM2 = smem;                  // [WPB][HD]
  ushortt* sW2 = sM2 + WPB * HD;
  ushortt* sH2 = sW2 + WPB * HD;
  ushortt* sM3 = sH2 + WPB * HD;

  // block-local vectors (fp16) + tiny cell state
  __shared__ __align__(16) ushortt s_TD1[HD], s_h1[HD], s_TD2[HD], s_h2[HD], s_h3[HD];
  __shared__ __align__(16) ushortt s_small[CD];  // TD0 feeding g1(t+1)
  __shared__ float s_gateA[WPB], s_gateB[WPB], s_rec[4];
  __shared__ float s_c1own[4], s_c2own[4], s_c3own[4];
  __shared__ __align__(16) float s_ftmp[HD];

  int ep = 0;
  float loss_acc = 0.f, fll_acc = 0.f;
  float b1, b2, b3, vbR3 = 0.f, vbR2 = 0.f, vbZ = 0.f;
  float part1 = 0.f, part2 = 0.f, part3 = 0.f;   // stale-operand partial dots

  // ---------------- prologue ------------------------------------------------
  {
    const uint4* gM2 = (const uint4*)(hM2   + (size_t)rg * HD);
    const uint4* gW2 = (const uint4*)(hW2b  + (size_t)rg * HD);
    const uint4* gH2 = (const uint4*)(hWhh2 + (size_t)rg * HD);
    const uint4* gM3 = (const uint4*)(hM3   + (size_t)rg * HD);
    uint4* lM2 = (uint4*)(sM2 + wv * HD);
    uint4* lW2 = (uint4*)(sW2 + wv * HD);
    uint4* lH2 = (uint4*)(sH2 + wv * HD);
    uint4* lM3 = (uint4*)(sM3 + wv * HD);
    #pragma unroll
    for (int i = 0; i < 2; ++i) {
      lM2[lane + 64 * i] = gM2[lane + 64 * i];
      lW2[lane + 64 * i] = gW2[lane + 64 * i];
      lH2[lane + 64 * i] = gH2[lane + 64 * i];
      lM3[lane + 64 * i] = gM3[lane + 64 * i];
    }
  }
  // fold biases (3 sequential rounds through s_ftmp)
  if (tid < 512) *(float2*)(s_ftmp + tid * 2) = *(const float2*)(Wb0 + tid * 2);
  __syncthreads();
  b1 = bih1[rg] + bhh1[rg] + wredsum(dotp(Wih1 + (size_t)rg * 2 * HD, s_ftmp, HD, lane));
  __syncthreads();
  if (tid < 512) *(float2*)(s_ftmp + tid * 2) = *(const float2*)(Wb1 + tid * 2);
  __syncthreads();
  b2 = bih2[rg] + bhh2[rg] + wredsum(dotp(Wih2 + (size_t)rg * 2 * HD, s_ftmp, HD, lane));
  __syncthreads();
  if (tid < 512) *(float2*)(s_ftmp + tid * 2) = *(const float2*)(Wb2 + tid * 2);
  __syncthreads();
  b3 = bih3[rg] + bhh3[rg] + wredsum(dotp(Wih3 + (size_t)rg * HD, s_ftmp, HD, lane));
  if (gi == 0) vbR3 = Vb3[jown];
  if (gi == 2) vbR2 = Vb2[jown];
  if (wv == 1) vbZ  = Vb1[bid];
  if (tid < 4) { s_c2own[tid] = 0.f; s_c3own[tid] = 0.f; }
  if (tid < NMIR) {                     // publish zero h2/TD2/h3 slices (all mirrors)
    uint2 z2 = make_uint2(0u, 0u);
    cstoreU2(d_h2m[tid] + bid * 4, z2);
    cstoreU2(d_TD2m[tid] + bid * 4, z2);
    cstoreU2(d_h3m[tid] + bid * 4, z2);
  }
  if (tid < 64) {                       // softmax(r1) -> TD0(0); loss0(0)
    float4 z4 = *(const float4*)(r1 + tid * 4);
    float m = wredmax(fmaxf(fmaxf(z4.x, z4.y), fmaxf(z4.z, z4.w)));
    float e0 = __expf(z4.x - m), e1 = __expf(z4.y - m);
    float e2 = __expf(z4.z - m), e3 = __expf(z4.w - m);
    float inv = 1.f / wredsum((e0 + e1) + (e2 + e3));
    float p0 = e0 * inv, p1 = e1 * inv, p2 = e2 * inv, p3 = e3 * inv;
    float4 xv = *(const float4*)(x + tid * 4);
    *(uint2*)(s_small + tid * 4) =
        make_uint2(packh2(xv.x - p0, xv.y - p1), packh2(xv.z - p2, xv.w - p3));
    if (iswg0) {
      float u = xv.x * __logf(p0) + (1.f - xv.x) * __logf(1.f - p0)
              + xv.y * __logf(p1) + (1.f - xv.y) * __logf(1.f - p1)
              + xv.z * __logf(p2) + (1.f - xv.z) * __logf(1.f - p2)
              + xv.w * __logf(p3) + (1.f - xv.w) * __logf(1.f - p3);
      u = wredsum(u);
      if (tid == 0) { loss_acc -= u; fll_acc -= u; }
    }
  }
  __syncthreads();
  {                                     // g1(0) rows (TD1=h1=0 at t=0)
    float s = wredsum(dotH256(hM1 + (size_t)rg * CD, s_small, lane)) + b1;
    if (lane == 0) s_gateA[wv] = s;
  }
  __syncthreads();
  if (tid < 64) {                       // cell1(0), rec2init = r2
    float h = 0.f, td = 0.f;
    if (lane < 4) {
      float gI = s_gateA[lane * 4 + 0];
      float gG = s_gateA[lane * 4 + 2], gO = s_gateA[lane * 4 + 3];
      float cn = sigf(gI) * tanhfast(gG);   // c1 = 0
      h  = sigf(gO) * tanhfast(cn);
      td = h - r2[bid * 4 + lane];
      s_c1own[lane] = cn;
    }
    uint2 uh, ut;
    uh.x = packh2(__shfl(h, 0), __shfl(h, 1));  uh.y = packh2(__shfl(h, 2), __shfl(h, 3));
    ut.x = packh2(__shfl(td, 0), __shfl(td, 1)); ut.y = packh2(__shfl(td, 2), __shfl(td, 3));
    if (lane < NMIR) { cstoreU2(d_h1m[lane] + bid * 4, uh); cstoreU2(d_TD1m[lane] + bid * 4, ut); }
  }
  // part2 for P(0): W2b@TD2(-1) + Whh2@h2(-1) = 0  (initial states are zero)
  part2 = 0.f;
  garrive(ep);
  gwait(ep);

  for (int t = 0; t < TT; ++t) {
    // ========== P(t): fresh {TD1,h1,h3}; g2 via part2; rec3, z1; cell2 ====
    {
      const int grp = tid >> 8, k = tid & 255;
      if (grp == 0)      *(uint2*)(s_TD1 + k * 4) = cloadU2(d_TD1m[mi] + k * 4);
      else if (grp == 1) *(uint2*)(s_h1 + k * 4)  = cloadU2(d_h1m[mi] + k * 4);
      else if (grp == 2) *(uint2*)(s_h3 + k * 4)  = cloadU2(d_h3m[mi] + k * 4);
      __syncthreads();
      if (w0) {                          // LAM * sum|TD1(t)|
        float a = 0.f;
        #pragma unroll
        for (int kk = 0; kk < 16; ++kk) a += fabsf(h2f(s_TD1[tid + 64 * kk]));
        a = wredsum(a);
        if (tid == 0) loss_acc += LAMF * a;
      }
      {                                  // g2 = M2@TD1 (LDS) + stale partial
        float s = wredsum(dotH(sM2 + wv * HD, s_TD1, lane)) + part2 + b2;
        if (lane == 0) s_gateA[wv] = s;
      }
      if (gi == 0) {                     // rec3(t-1) row for own element
        if (t > 0) {
          float s = wredsum(dotH(hVw3 + (size_t)jown * HD, s_h3, lane)) + vbR3;
          if (lane == 0) s_rec[slot] = s;
        } else if (lane == 0) s_rec[slot] = r3[jown];
      }
      if (wv == 1) {                     // z1 row bid -> all mirrors
        float s = wredsum(dotH(hVw1 + (size_t)bid * HD, s_h1, lane)) + vbZ;
        if (lane < NMIR) cstore(&d_z1m[lane][bid], s);
      }
      __syncthreads();
      if (tid < 64) {                    // cell2(t) -> publish h2,TD2 (mirrors)
        float h = 0.f, td = 0.f;
        if (lane < 4) {
          float gI = s_gateA[lane * 4 + 0], gF = s_gateA[lane * 4 + 1];
          float gG = s_gateA[lane * 4 + 2], gO = s_gateA[lane * 4 + 3];
          float cn = sigf(gF) * s_c2own[lane] + sigf(gI) * tanhfast(gG);
          h  = sigf(gO) * tanhfast(cn);
          td = h - s_rec[lane];
          s_c2own[lane] = cn;
        }
        uint2 uh, ut;
        uh.x = packh2(__shfl(h, 0), __shfl(h, 1));  uh.y = packh2(__shfl(h, 2), __shfl(h, 3));
        ut.x = packh2(__shfl(td, 0), __shfl(td, 1)); ut.y = packh2(__shfl(td, 2), __shfl(td, 3));
        if (lane < NMIR) { cstoreU2(d_h2m[lane] + bid * 4, uh); cstoreU2(d_TD2m[lane] + bid * 4, ut); }
      }
      garrive(ep);                       // arrive FIRST (publish visible)
      // precompute for Q(t) inside the gather window
      part3 = wredsum(dotH(hWhh3 + (size_t)rg * HD, s_h3, lane));
      part1 = wredsum(dotH(hW1b  + (size_t)rg * HD, s_TD1, lane)
                    + dotH(hWhh1 + (size_t)rg * HD, s_h1,  lane));
      gwait(ep);
    }

    // ========== Q(t): fresh {TD2,h2}; softmax; g3,g1 via partials; cells ==
    {
      const int grp = tid >> 8, k = tid & 255;
      if (grp == 0)      *(uint2*)(s_TD2 + k * 4) = cloadU2(d_TD2m[mi] + k * 4);
      else if (grp == 1) *(uint2*)(s_h2 + k * 4)  = cloadU2(d_h2m[mi] + k * 4);
      if (tid < 64) {                    // softmax(z1(t))
        float2 za = cload2(&d_z1m[mi][tid * 4]), zb = cload2(&d_z1m[mi][tid * 4 + 2]);
        float m = wredmax(fmaxf(fmaxf(za.x, za.y), fmaxf(zb.x, zb.y)));
        float e0 = __expf(za.x - m), e1 = __expf(za.y - m);
        float e2 = __expf(zb.x - m), e3 = __expf(zb.y - m);
        float inv = 1.f / wredsum((e0 + e1) + (e2 + e3));
        float p0 = e0 * inv, p1 = e1 * inv, p2 = e2 * inv, p3 = e3 * inv;
        if (t < TT - 1) {
          float4 xv = *(const float4*)(x + (size_t)(t + 1) * CD + tid * 4);
          *(uint2*)(s_small + tid * 4) =
              make_uint2(packh2(xv.x - p0, xv.y - p1), packh2(xv.z - p2, xv.w - p3));
          if (iswg0) {
            float u = xv.x * __logf(p0) + (1.f - xv.x) * __logf(1.f - p0)
                    + xv.y * __logf(p1) + (1.f - xv.y) * __logf(1.f - p1)
                    + xv.z * __logf(p2) + (1.f - xv.z) * __logf(1.f - p2)
                    + xv.w * __logf(p3) + (1.f - xv.w) * __logf(1.f - p3);
            u = wredsum(u);
            if (tid == 0) { loss_acc -= u; fll_acc -= u; }
          }
        }
        if (iswg0) {
          float* po = out + 2 + (size_t)t * CD + tid * 4;
          po[0] = p0; po[1] = p1; po[2] = p2; po[3] = p3;
        }
      }
      __syncthreads();
      if (w0) {                          // LAM^2 * sum|TD2(t)|
        float a = 0.f;
        #pragma unroll
        for (int kk = 0; kk < 16; ++kk) a += fabsf(h2f(s_TD2[tid + 64 * kk]));
        a = wredsum(a);
        if (tid == 0) loss_acc += (LAMF * LAMF) * a;
      }
      if (t < TT - 1) {
        {                                // g3 = M3@TD2 (LDS) + part3
          float s = wredsum(dotH(sM3 + wv * HD, s_TD2, lane)) + part3 + b3;
          if (lane == 0) s_gateB[wv] = s;
        }
        {                                // g1(t+1) = M1@TD0 + part1
          float s = wredsum(dotH256(hM1 + (size_t)rg * CD, s_small, lane)) + part1 + b1;
          if (lane == 0) s_gateA[wv] = s;
        }
        if (gi == 2) {                   // rec2(t) row for own element
          float s = wredsum(dotH(hVw2 + (size_t)jown * HD, s_h2, lane)) + vbR2;
          if (lane == 0) s_rec[slot] = s;
        }
        __syncthreads();
        if (tid < 64) {                  // cell3(t) + cell1(t+1) -> publish (mirrors)
          float h3n = 0.f, h1n = 0.f, td1 = 0.f;
          if (lane < 4) {
            {
              float gI = s_gateB[lane * 4 + 0], gF = s_gateB[lane * 4 + 1];
              float gG = s_gateB[lane * 4 + 2], gO = s_gateB[lane * 4 + 3];
              float cn = sigf(gF) * s_c3own[lane] + sigf(gI) * tanhfast(gG);
              h3n = sigf(gO) * tanhfast(cn);
              s_c3own[lane] = cn;
            }
            {
              float gI = s_gateA[lane * 4 + 0], gF = s_gateA[lane * 4 + 1];
              float gG = s_gateA[lane * 4 + 2], gO = s_gateA[lane * 4 + 3];
              float cn = sigf(gF) * s_c1own[lane] + sigf(gI) * tanhfast(gG);
              h1n = sigf(gO) * tanhfast(cn);
              td1 = h1n - s_rec[lane];
              s_c1own[lane] = cn;
            }
          }
          uint2 u3, u1, utd;
          u3.x = packh2(__shfl(h3n, 0), __shfl(h3n, 1)); u3.y = packh2(__shfl(h3n, 2), __shfl(h3n, 3));
          u1.x = packh2(__shfl(h1n, 0), __shfl(h1n, 1)); u1.y = packh2(__shfl(h1n, 2), __shfl(h1n, 3));
          utd.x = packh2(__shfl(td1, 0), __shfl(td1, 1)); utd.y = packh2(__shfl(td1, 2), __shfl(td1, 3));
          if (lane < NMIR) {
            cstoreU2(d_h3m[lane] + bid * 4, u3);
            cstoreU2(d_h1m[lane] + bid * 4, u1);
            cstoreU2(d_TD1m[lane] + bid * 4, utd);
          }
        }
        garrive(ep);                     // arrive FIRST
        // precompute for P(t+1): W2b@TD2(t)+Whh2@h2(t) (LDS rows)
        part2 = wredsum(dotH(sW2 + wv * HD, s_TD2, lane)
                      + dotH(sH2 + wv * HD, s_h2,  lane));
        gwait(ep);
      }
    }
  }

  if (iswg0 && tid == 0) { out[0] = loss_acc; out[1] = fll_acc; }
}

extern "C" void kernel_launch(void* const* d_in, const int* in_sizes, int n_in,
                              void* d_out, int out_size, void* d_ws, size_t ws_size,
                              hipStream_t stream) {
  const float* x    = (const float*)d_in[0];
  const float* Wih1 = (const float*)d_in[1];
  const float* Whh1 = (const float*)d_in[2];
  const float* bih1 = (const float*)d_in[3];
  const float* bhh1 = (const float*)d_in[4];
  const float* Vw1  = (const float*)d_in[5];
  const float* Vb1  = (const float*)d_in[6];
  const float* Wih2 = (const float*)d_in[7];
  const float* Whh2 = (const float*)d_in[8];
  const float* bih2 = (const float*)d_in[9];
  const float* bhh2 = (const float*)d_in[10];
  const float* Vw2  = (const float*)d_in[11];
  const float* Vb2  = (const float*)d_in[12];
  const float* Wih3 = (const float*)d_in[13];
  const float* Whh3 = (const float*)d_in[14];
  const float* bih3 = (const float*)d_in[15];
  const float* bhh3 = (const float*)d_in[16];
  const float* Vw3  = (const float*)d_in[17];
  const float* Vb3  = (const float*)d_in[18];
  const float* Ww0  = (const float*)d_in[19];
  const float* Wb0  = (const float*)d_in[20];
  const float* Ww1  = (const float*)d_in[21];
  const float* Wb1  = (const float*)d_in[22];
  const float* Ww2  = (const float*)d_in[23];
  const float* Wb2  = (const float*)d_in[24];
  const float* r1   = (const float*)d_in[25];
  const float* r2   = (const float*)d_in[26];
  const float* r3   = (const float*)d_in[27];

  static int smem_set = 0;
  if (!smem_set) {
    hipFuncSetAttribute((const void*)pc_main,
                        hipFuncAttributeMaxDynamicSharedMemorySize, SMEMB);
    smem_set = 1;
  }

  pc_conv<<<1024, 256, 0, stream>>>(Wih1, Whh1, Wih2, Whh2, Whh3, Vw1, Vw2, Vw3);
  pc_fold<<<2304, 256, 0, stream>>>(Wih1, Wih2, Wih3, Ww0, Ww1, Ww2);
  pc_init<<<1, NWG, 0, stream>>>();
  pc_main<<<NWG, NTH, SMEMB, stream>>>(x, Wih1, Whh1, bih1, bhh1, Vw1, Vb1,
                                       Wih2, Whh2, bih2, bhh2, Vw2, Vb2,
                                       Wih3, Whh3, bih3, bhh3, Vw3, Vb3,
                                       Ww0, Wb0, Ww1, Wb1, Ww2, Wb2,
                                       r1, r2, r3, (float*)d_out);
}

// Round 16
// 7529.398 us; speedup vs baseline: 1.1904x; 1.1904x over previous
//
#include <hip/hip_runtime.h>
#include <math.h>

#define HD 1024
#define CD 256
#define TT 512
#define GD 4096                 // 4*H
#define NWG 256
#define NTH 1024
#define WPB 16                  // waves per block
#define LAMF 0.05f
#define SMEMB (4 * WPB * HD * 2)   // 128 KB dynamic LDS: M2,W2b,Whh2,M3 rows

typedef unsigned long long ull;
typedef unsigned short ushortt;
typedef _Float16 hh2 __attribute__((ext_vector_type(2)));

// ---------------- fp16 weight copies (built per call) ---------------------
__device__ __align__(16) ushortt hM1[GD * CD];    //  2 MB : Wih1[:,:H]@Ww0
__device__ __align__(16) ushortt hM2[GD * HD];    //  8 MB : Wih2[:,:H]@Ww1
__device__ __align__(16) ushortt hM3[GD * HD];    //  8 MB : Wih3@Ww2
__device__ __align__(16) ushortt hW1b[GD * HD];   //  8 MB : Wih1[:,H:]
__device__ __align__(16) ushortt hWhh1[GD * HD];  //  8 MB
__device__ __align__(16) ushortt hW2b[GD * HD];   //  8 MB : Wih2[:,H:]
__device__ __align__(16) ushortt hWhh2[GD * HD];  //  8 MB
__device__ __align__(16) ushortt hWhh3[GD * HD];  //  8 MB
__device__ __align__(16) ushortt hVw1[CD * HD];   // .5 MB
__device__ __align__(16) ushortt hVw2[HD * HD];   //  2 MB
__device__ __align__(16) ushortt hVw3[HD * HD];   //  2 MB

// ---------------- published cross-WG state (fp16 vectors + z1) ------------
__device__ __align__(8) ushortt d_h1h[HD], d_TD1h[HD], d_h3h[HD];
__device__ __align__(8) ushortt d_h2h[HD], d_TD2h[HD];   // single buffer
__device__ __align__(16) float d_z1[CD];
// two-hop distributed barrier (R3-proven): per-WG flag line + release line
__device__ int d_arr[NWG][32];
__device__ int d_rel;

__global__ void pc_init() { d_arr[threadIdx.x][0] = 0; if (threadIdx.x == 0) d_rel = 0; }

__device__ __forceinline__ float sigf(float x)     { return 1.f / (1.f + __expf(-x)); }
__device__ __forceinline__ float tanhfast(float x) { return 1.f - 2.f / (1.f + __expf(2.f * x)); }

__device__ __forceinline__ float h2f(ushortt u) {
  union { ushortt u; _Float16 h; } c; c.u = u; return (float)c.h;
}
__device__ __forceinline__ unsigned packh2(float a, float b) {
  union { unsigned u; hh2 h; } c; c.h = hh2{(_Float16)a, (_Float16)b}; return c.u;
}
__device__ __forceinline__ float fd2(unsigned a, unsigned b, float c) {
  union { unsigned u; hh2 h; } ua, ub; ua.u = a; ub.u = b;
  return __builtin_amdgcn_fdot2(ua.h, ub.h, c, false);
}

__device__ __forceinline__ float cload(const float* p) {
  return __hip_atomic_load(p, __ATOMIC_RELAXED, __HIP_MEMORY_SCOPE_AGENT);
}
__device__ __forceinline__ void cstore(float* p, float v) {
  __hip_atomic_store(p, v, __ATOMIC_RELAXED, __HIP_MEMORY_SCOPE_AGENT);
}
__device__ __forceinline__ float2 cload2(const float* p) {
  union { ull u; float2 f; } c;
  c.u = __hip_atomic_load((const ull*)p, __ATOMIC_RELAXED, __HIP_MEMORY_SCOPE_AGENT);
  return c.f;
}
__device__ __forceinline__ uint2 cloadU2(const ushortt* p) {
  union { ull u; uint2 v; } c;
  c.u = __hip_atomic_load((const ull*)p, __ATOMIC_RELAXED, __HIP_MEMORY_SCOPE_AGENT);
  return c.v;
}
__device__ __forceinline__ void cstoreU2(ushortt* p, uint2 v) {
  union { ull u; uint2 v; } c; c.v = v;
  __hip_atomic_store((ull*)p, c.u, __ATOMIC_RELAXED, __HIP_MEMORY_SCOPE_AGENT);
}

// Two-hop distributed epoch barrier (R3-proven; no cache-invalidating fences).
__device__ __forceinline__ void gbar(int& ep) {
  ++ep;
  __syncthreads();
  const int tid = threadIdx.x;
  if (blockIdx.x == 0) {
    if (tid >= 1 && tid < NWG) {
      while (__hip_atomic_load(&d_arr[tid][0], __ATOMIC_RELAXED, __HIP_MEMORY_SCOPE_AGENT) < ep)
        __builtin_amdgcn_s_sleep(1);
    }
    __syncthreads();
    if (tid == 0)
      __hip_atomic_store(&d_rel, ep, __ATOMIC_RELEASE, __HIP_MEMORY_SCOPE_AGENT);
  } else {
    if (tid == 0) {
      __hip_atomic_store(&d_arr[blockIdx.x][0], ep, __ATOMIC_RELEASE, __HIP_MEMORY_SCOPE_AGENT);
      while (__hip_atomic_load(&d_rel, __ATOMIC_RELAXED, __HIP_MEMORY_SCOPE_AGENT) < ep)
        __builtin_amdgcn_s_sleep(1);
    }
    __syncthreads();
  }
}

__device__ __forceinline__ float wredsum(float v) {
  #pragma unroll
  for (int off = 32; off; off >>= 1) v += __shfl_xor(v, off);
  return v;
}
__device__ __forceinline__ float wredmax(float v) {
  #pragma unroll
  for (int off = 32; off; off >>= 1) v = fmaxf(v, __shfl_xor(v, off));
  return v;
}

// fp32 dot (prologue only)
__device__ __forceinline__ float dotp(const float* __restrict__ w, const float* xv, int n, int lane) {
  float a0 = 0.f, a1 = 0.f, a2 = 0.f, a3 = 0.f;
  for (int c = lane * 4; c < n; c += 256) {
    const float4 wv = *(const float4*)(w + c);
    const float4 vv = *(const float4*)(xv + c);
    a0 = fmaf(wv.x, vv.x, a0); a1 = fmaf(wv.y, vv.y, a1);
    a2 = fmaf(wv.z, vv.z, a2); a3 = fmaf(wv.w, vv.w, a3);
  }
  return (a0 + a1) + (a2 + a3);
}

// fp16 dot over 1024 halves (weight row pointer: global OR LDS)
__device__ __forceinline__ float dotH(const ushortt* __restrict__ w, const ushortt* xv, int lane) {
  const uint4 w0 = *(const uint4*)(w + lane * 8);
  const uint4 w1 = *(const uint4*)(w + lane * 8 + 512);
  const uint4 v0 = *(const uint4*)(xv + lane * 8);
  const uint4 v1 = *(const uint4*)(xv + lane * 8 + 512);
  float a = 0.f;
  a = fd2(w0.x, v0.x, a); a = fd2(w0.y, v0.y, a);
  a = fd2(w0.z, v0.z, a); a = fd2(w0.w, v0.w, a);
  a = fd2(w1.x, v1.x, a); a = fd2(w1.y, v1.y, a);
  a = fd2(w1.z, v1.z, a); a = fd2(w1.w, v1.w, a);
  return a;
}
// fp16 dot over 256 halves
__device__ __forceinline__ float dotH256(const ushortt* __restrict__ w, const ushortt* xv, int lane) {
  const uint2 wv = *(const uint2*)(w + lane * 4);
  const uint2 vv = *(const uint2*)(xv + lane * 4);
  float a = fd2(wv.x, vv.x, 0.f);
  return fd2(wv.y, vv.y, a);
}

// ---------------- fp32->fp16 weight conversion (float2-vectorized) --------
__global__ __launch_bounds__(256) void pc_conv(
    const float* __restrict__ Wih1, const float* __restrict__ Whh1,
    const float* __restrict__ Wih2, const float* __restrict__ Whh2,
    const float* __restrict__ Whh3, const float* __restrict__ Vw1,
    const float* __restrict__ Vw2,  const float* __restrict__ Vw3) {
  const size_t stride = (size_t)gridDim.x * 256;
  const size_t i0 = (size_t)blockIdx.x * 256 + threadIdx.x;
  for (size_t i = i0; i < (size_t)GD * HD / 2; i += stride) {
    const size_t j = i * 2;
    const size_t r = j >> 10, c = j & 1023;
    const size_t src = (r << 11) + HD + c;      // even c -> aligned float2
    float2 a;
    a = *(const float2*)(Wih1 + src); *(unsigned*)(hW1b + j)  = packh2(a.x, a.y);
    a = *(const float2*)(Wih2 + src); *(unsigned*)(hW2b + j)  = packh2(a.x, a.y);
    a = *(const float2*)(Whh1 + j);   *(unsigned*)(hWhh1 + j) = packh2(a.x, a.y);
    a = *(const float2*)(Whh2 + j);   *(unsigned*)(hWhh2 + j) = packh2(a.x, a.y);
    a = *(const float2*)(Whh3 + j);   *(unsigned*)(hWhh3 + j) = packh2(a.x, a.y);
  }
  for (size_t i = i0; i < (size_t)HD * HD / 2; i += stride) {
    const size_t j = i * 2;
    float2 a;
    a = *(const float2*)(Vw2 + j); *(unsigned*)(hVw2 + j) = packh2(a.x, a.y);
    a = *(const float2*)(Vw3 + j); *(unsigned*)(hVw3 + j) = packh2(a.x, a.y);
  }
  for (size_t i = i0; i < (size_t)CD * HD / 2; i += stride) {
    const size_t j = i * 2;
    float2 a = *(const float2*)(Vw1 + j);
    *(unsigned*)(hVw1 + j) = packh2(a.x, a.y);
  }
}

// ---------------- fold GEMM: fp16 C[4096 x N] = A @ B ---------------------
__global__ __launch_bounds__(256) void pc_fold(
    const float* __restrict__ Wih1, const float* __restrict__ Wih2,
    const float* __restrict__ Wih3, const float* __restrict__ Ww0,
    const float* __restrict__ Ww1,  const float* __restrict__ Ww2) {
  int b = blockIdx.x;
  const float* A; const float* B; ushortt* C; int N, lda;
  if (b < 256)        { A = Wih1; B = Ww0; C = hM1; N = CD; lda = 2 * HD; }
  else if (b < 1280)  { A = Wih2; B = Ww1; C = hM2; N = HD; lda = 2 * HD; b -= 256; }
  else                { A = Wih3; B = Ww2; C = hM3; N = HD; lda = HD;     b -= 1280; }
  const int ctiles = N >> 6;
  const int rt = b / ctiles, ct = b - rt * ctiles;
  const int tid = threadIdx.x;
  const int tx = tid & 15, ty = tid >> 4;

  __shared__ float sA[16][65];
  __shared__ float sB[16][64];

  float acc[4][4] = {};
  const int ar = tid >> 2, aq = tid & 3;
  const int br = tid >> 4, bq = tid & 15;

  for (int kk = 0; kk < HD; kk += 16) {
    float4 av = *(const float4*)(A + (size_t)(rt * 64 + ar) * lda + kk + aq * 4);
    float4 bv = *(const float4*)(B + (size_t)(kk + br) * N + ct * 64 + bq * 4);
    __syncthreads();
    sA[aq * 4 + 0][ar] = av.x; sA[aq * 4 + 1][ar] = av.y;
    sA[aq * 4 + 2][ar] = av.z; sA[aq * 4 + 3][ar] = av.w;
    *(float4*)&sB[br][bq * 4] = bv;
    __syncthreads();
    #pragma unroll
    for (int k = 0; k < 16; ++k) {
      const float4 b4 = *(const float4*)&sB[k][tx * 4];
      const float a0 = sA[k][ty * 4 + 0], a1 = sA[k][ty * 4 + 1];
      const float a2 = sA[k][ty * 4 + 2], a3 = sA[k][ty * 4 + 3];
      acc[0][0] = fmaf(a0, b4.x, acc[0][0]); acc[0][1] = fmaf(a0, b4.y, acc[0][1]);
      acc[0][2] = fmaf(a0, b4.z, acc[0][2]); acc[0][3] = fmaf(a0, b4.w, acc[0][3]);
      acc[1][0] = fmaf(a1, b4.x, acc[1][0]); acc[1][1] = fmaf(a1, b4.y, acc[1][1]);
      acc[1][2] = fmaf(a1, b4.z, acc[1][2]); acc[1][3] = fmaf(a1, b4.w, acc[1][3]);
      acc[2][0] = fmaf(a2, b4.x, acc[2][0]); acc[2][1] = fmaf(a2, b4.y, acc[2][1]);
      acc[2][2] = fmaf(a2, b4.z, acc[2][2]); acc[2][3] = fmaf(a2, b4.w, acc[2][3]);
      acc[3][0] = fmaf(a3, b4.x, acc[3][0]); acc[3][1] = fmaf(a3, b4.y, acc[3][1]);
      acc[3][2] = fmaf(a3, b4.z, acc[3][2]); acc[3][3] = fmaf(a3, b4.w, acc[3][3]);
    }
  }
  #pragma unroll
  for (int i = 0; i < 4; ++i) {
    uint2 r = make_uint2(packh2(acc[i][0], acc[i][1]), packh2(acc[i][2], acc[i][3]));
    *(uint2*)(C + (size_t)(rt * 64 + ty * 4 + i) * N + ct * 64 + tx * 4) = r;
  }
}

__global__ __launch_bounds__(NTH, 1) void pc_main(
    const float* __restrict__ x,
    const float* __restrict__ Wih1, const float* __restrict__ Whh1,
    const float* __restrict__ bih1, const float* __restrict__ bhh1,
    const float* __restrict__ Vw1,  const float* __restrict__ Vb1,
    const float* __restrict__ Wih2, const float* __restrict__ Whh2,
    const float* __restrict__ bih2, const float* __restrict__ bhh2,
    const float* __restrict__ Vw2,  const float* __restrict__ Vb2,
    const float* __restrict__ Wih3, const float* __restrict__ Whh3,
    const float* __restrict__ bih3, const float* __restrict__ bhh3,
    const float* __restrict__ Vw3,  const float* __restrict__ Vb3,
    const float* __restrict__ Ww0,  const float* __restrict__ Wb0,
    const float* __restrict__ Ww1,  const float* __restrict__ Wb1,
    const float* __restrict__ Ww2,  const float* __restrict__ Wb2,
    const float* __restrict__ r1,   const float* __restrict__ r2,
    const float* __restrict__ r3,
    float* __restrict__ out) {
  const int tid  = threadIdx.x;
  const int lane = tid & 63;
  const int bid  = blockIdx.x;
  const int wv   = tid >> 6;            // wave index within block
  const int gi   = wv & 3;              // gate index (i,f,g,o)
  const int slot = wv >> 2;             // owned-element slot 0..3
  const int rg   = gi * HD + bid * 4 + slot;   // this wave's gate row
  const int jown = bid * 4 + slot;      // element for rec/z rows
  const bool iswg0 = (bid == 0);
  const bool w0    = iswg0 && tid < 64;

  // dynamic LDS: per-wave private weight rows
  extern __shared__ __align__(16) ushortt smem[];
  ushortt* sM2 = smem;                  // [WPB][HD]
  ushortt* sW2 = sM2 + WPB * HD;
  ushortt* sH2 = sW2 + WPB * HD;
  ushortt* sM3 = sH2 + WPB * HD;

  // block-local vectors (fp16) + tiny cell state
  __shared__ __align__(16) ushortt s_TD1[HD], s_h1[HD], s_TD2[HD], s_h2[HD], s_h3[HD];
  __shared__ __align__(16) ushortt s_small[CD];  // TD0 feeding g1(t+1)
  __shared__ float s_gateA[WPB], s_gateB[WPB], s_rec[4];
  __shared__ float s_c1own[4], s_c2own[4], s_c3own[4];
  __shared__ __align__(16) float s_ftmp[HD];

  int ep = 0;
  float loss_acc = 0.f, fll_acc = 0.f;
  float b1, b2, b3, vbR3 = 0.f, vbR2 = 0.f, vbZ = 0.f;
  float part1 = 0.f, part2 = 0.f, part3 = 0.f;   // stale-operand partial dots

  // ---------------- prologue ------------------------------------------------
  {
    const uint4* gM2 = (const uint4*)(hM2   + (size_t)rg * HD);
    const uint4* gW2 = (const uint4*)(hW2b  + (size_t)rg * HD);
    const uint4* gH2 = (const uint4*)(hWhh2 + (size_t)rg * HD);
    const uint4* gM3 = (const uint4*)(hM3   + (size_t)rg * HD);
    uint4* lM2 = (uint4*)(sM2 + wv * HD);
    uint4* lW2 = (uint4*)(sW2 + wv * HD);
    uint4* lH2 = (uint4*)(sH2 + wv * HD);
    uint4* lM3 = (uint4*)(sM3 + wv * HD);
    #pragma unroll
    for (int i = 0; i < 2; ++i) {
      lM2[lane + 64 * i] = gM2[lane + 64 * i];
      lW2[lane + 64 * i] = gW2[lane + 64 * i];
      lH2[lane + 64 * i] = gH2[lane + 64 * i];
      lM3[lane + 64 * i] = gM3[lane + 64 * i];
    }
  }
  // fold biases (3 sequential rounds through s_ftmp)
  if (tid < 512) *(float2*)(s_ftmp + tid * 2) = *(const float2*)(Wb0 + tid * 2);
  __syncthreads();
  b1 = bih1[rg] + bhh1[rg] + wredsum(dotp(Wih1 + (size_t)rg * 2 * HD, s_ftmp, HD, lane));
  __syncthreads();
  if (tid < 512) *(float2*)(s_ftmp + tid * 2) = *(const float2*)(Wb1 + tid * 2);
  __syncthreads();
  b2 = bih2[rg] + bhh2[rg] + wredsum(dotp(Wih2 + (size_t)rg * 2 * HD, s_ftmp, HD, lane));
  __syncthreads();
  if (tid < 512) *(float2*)(s_ftmp + tid * 2) = *(const float2*)(Wb2 + tid * 2);
  __syncthreads();
  b3 = bih3[rg] + bhh3[rg] + wredsum(dotp(Wih3 + (size_t)rg * HD, s_ftmp, HD, lane));
  if (gi == 0) vbR3 = Vb3[jown];
  if (gi == 2) vbR2 = Vb2[jown];
  if (wv == 1) vbZ  = Vb1[bid];
  if (tid < 4) { s_c2own[tid] = 0.f; s_c3own[tid] = 0.f; }
  if (tid == 0) {                       // publish zero h2/TD2/h3 slices
    uint2 z2 = make_uint2(0u, 0u);
    cstoreU2(d_h2h + bid * 4, z2);
    cstoreU2(d_TD2h + bid * 4, z2);
    cstoreU2(d_h3h + bid * 4, z2);
  }
  if (tid < 64) {                       // softmax(r1) -> TD0(0); loss0(0)
    float4 z4 = *(const float4*)(r1 + tid * 4);
    float m = wredmax(fmaxf(fmaxf(z4.x, z4.y), fmaxf(z4.z, z4.w)));
    float e0 = __expf(z4.x - m), e1 = __expf(z4.y - m);
    float e2 = __expf(z4.z - m), e3 = __expf(z4.w - m);
    float inv = 1.f / wredsum((e0 + e1) + (e2 + e3));
    float p0 = e0 * inv, p1 = e1 * inv, p2 = e2 * inv, p3 = e3 * inv;
    float4 xv = *(const float4*)(x + tid * 4);
    *(uint2*)(s_small + tid * 4) =
        make_uint2(packh2(xv.x - p0, xv.y - p1), packh2(xv.z - p2, xv.w - p3));
    if (iswg0) {
      float u = xv.x * __logf(p0) + (1.f - xv.x) * __logf(1.f - p0)
              + xv.y * __logf(p1) + (1.f - xv.y) * __logf(1.f - p1)
              + xv.z * __logf(p2) + (1.f - xv.z) * __logf(1.f - p2)
              + xv.w * __logf(p3) + (1.f - xv.w) * __logf(1.f - p3);
      u = wredsum(u);
      if (tid == 0) { loss_acc -= u; fll_acc -= u; }
    }
  }
  __syncthreads();
  {                                     // g1(0) rows (TD1=h1=0 at t=0)
    float s = wredsum(dotH256(hM1 + (size_t)rg * CD, s_small, lane)) + b1;
    if (lane == 0) s_gateA[wv] = s;
  }
  __syncthreads();
  if (tid < 64) {                       // cell1(0), rec2init = r2
    float h = 0.f, td = 0.f;
    if (lane < 4) {
      float gI = s_gateA[lane * 4 + 0];
      float gG = s_gateA[lane * 4 + 2], gO = s_gateA[lane * 4 + 3];
      float cn = sigf(gI) * tanhfast(gG);   // c1 = 0
      h  = sigf(gO) * tanhfast(cn);
      td = h - r2[bid * 4 + lane];
      s_c1own[lane] = cn;
    }
    uint2 uh, ut;
    uh.x = packh2(__shfl(h, 0), __shfl(h, 1));  uh.y = packh2(__shfl(h, 2), __shfl(h, 3));
    ut.x = packh2(__shfl(td, 0), __shfl(td, 1)); ut.y = packh2(__shfl(td, 2), __shfl(td, 3));
    if (lane == 0) { cstoreU2(d_h1h + bid * 4, uh); cstoreU2(d_TD1h + bid * 4, ut); }
  }
  // part2 for P(0): W2b@TD2(-1) + Whh2@h2(-1) = 0  (initial states are zero)
  part2 = 0.f;
  gbar(ep);

  for (int t = 0; t < TT; ++t) {
    // ========== P(t): fresh {TD1,h1,h3}; g2 via part2; rec3, z1; cell2 ====
    {
      const int grp = tid >> 8, k = tid & 255;
      if (grp == 0)      *(uint2*)(s_TD1 + k * 4) = cloadU2(d_TD1h + k * 4);
      else if (grp == 1) *(uint2*)(s_h1 + k * 4)  = cloadU2(d_h1h + k * 4);
      else if (grp == 2) *(uint2*)(s_h3 + k * 4)  = cloadU2(d_h3h + k * 4);
      __syncthreads();
      if (w0) {                          // LAM * sum|TD1(t)|
        float a = 0.f;
        #pragma unroll
        for (int kk = 0; kk < 16; ++kk) a += fabsf(h2f(s_TD1[tid + 64 * kk]));
        a = wredsum(a);
        if (tid == 0) loss_acc += LAMF * a;
      }
      {                                  // g2 = M2@TD1 (LDS) + stale partial
        float s = wredsum(dotH(sM2 + wv * HD, s_TD1, lane)) + part2 + b2;
        if (lane == 0) s_gateA[wv] = s;
      }
      if (gi == 0) {                     // rec3(t-1) row for own element
        if (t > 0) {
          float s = wredsum(dotH(hVw3 + (size_t)jown * HD, s_h3, lane)) + vbR3;
          if (lane == 0) s_rec[slot] = s;
        } else if (lane == 0) s_rec[slot] = r3[jown];
      }
      if (wv == 1) {                     // z1 row bid
        float s = wredsum(dotH(hVw1 + (size_t)bid * HD, s_h1, lane)) + vbZ;
        if (lane == 0) cstore(&d_z1[bid], s);
      }
      __syncthreads();
      if (tid < 64) {                    // cell2(t) -> publish h2,TD2
        float h = 0.f, td = 0.f;
        if (lane < 4) {
          float gI = s_gateA[lane * 4 + 0], gF = s_gateA[lane * 4 + 1];
          float gG = s_gateA[lane * 4 + 2], gO = s_gateA[lane * 4 + 3];
          float cn = sigf(gF) * s_c2own[lane] + sigf(gI) * tanhfast(gG);
          h  = sigf(gO) * tanhfast(cn);
          td = h - s_rec[lane];
          s_c2own[lane] = cn;
        }
        uint2 uh, ut;
        uh.x = packh2(__shfl(h, 0), __shfl(h, 1));  uh.y = packh2(__shfl(h, 2), __shfl(h, 3));
        ut.x = packh2(__shfl(td, 0), __shfl(td, 1)); ut.y = packh2(__shfl(td, 2), __shfl(td, 3));
        if (lane == 0) { cstoreU2(d_h2h + bid * 4, uh); cstoreU2(d_TD2h + bid * 4, ut); }
      }
      // AFTER publish: precompute for Q(t) from operands fresh-read this phase
      part3 = wredsum(dotH(hWhh3 + (size_t)rg * HD, s_h3, lane));
      part1 = wredsum(dotH(hW1b  + (size_t)rg * HD, s_TD1, lane)
                    + dotH(hWhh1 + (size_t)rg * HD, s_h1,  lane));
    }
    gbar(ep);

    // ========== Q(t): fresh {TD2,h2}; softmax; g3,g1 via partials; cells ==
    {
      const int grp = tid >> 8, k = tid & 255;
      if (grp == 0)      *(uint2*)(s_TD2 + k * 4) = cloadU2(d_TD2h + k * 4);
      else if (grp == 1) *(uint2*)(s_h2 + k * 4)  = cloadU2(d_h2h + k * 4);
      if (tid < 64) {                    // softmax(z1(t))
        float2 za = cload2(&d_z1[tid * 4]), zb = cload2(&d_z1[tid * 4 + 2]);
        float m = wredmax(fmaxf(fmaxf(za.x, za.y), fmaxf(zb.x, zb.y)));
        float e0 = __expf(za.x - m), e1 = __expf(za.y - m);
        float e2 = __expf(zb.x - m), e3 = __expf(zb.y - m);
        float inv = 1.f / wredsum((e0 + e1) + (e2 + e3));
        float p0 = e0 * inv, p1 = e1 * inv, p2 = e2 * inv, p3 = e3 * inv;
        if (t < TT - 1) {
          float4 xv = *(const float4*)(x + (size_t)(t + 1) * CD + tid * 4);
          *(uint2*)(s_small + tid * 4) =
              make_uint2(packh2(xv.x - p0, xv.y - p1), packh2(xv.z - p2, xv.w - p3));
          if (iswg0) {
            float u = xv.x * __logf(p0) + (1.f - xv.x) * __logf(1.f - p0)
                    + xv.y * __logf(p1) + (1.f - xv.y) * __logf(1.f - p1)
                    + xv.z * __logf(p2) + (1.f - xv.z) * __logf(1.f - p2)
                    + xv.w * __logf(p3) + (1.f - xv.w) * __logf(1.f - p3);
            u = wredsum(u);
            if (tid == 0) { loss_acc -= u; fll_acc -= u; }
          }
        }
        if (iswg0) {
          float* po = out + 2 + (size_t)t * CD + tid * 4;
          po[0] = p0; po[1] = p1; po[2] = p2; po[3] = p3;
        }
      }
      __syncthreads();
      if (w0) {                          // LAM^2 * sum|TD2(t)|
        float a = 0.f;
        #pragma unroll
        for (int kk = 0; kk < 16; ++kk) a += fabsf(h2f(s_TD2[tid + 64 * kk]));
        a = wredsum(a);
        if (tid == 0) loss_acc += (LAMF * LAMF) * a;
      }
      if (t < TT - 1) {
        {                                // g3 = M3@TD2 (LDS) + part3
          float s = wredsum(dotH(sM3 + wv * HD, s_TD2, lane)) + part3 + b3;
          if (lane == 0) s_gateB[wv] = s;
        }
        {                                // g1(t+1) = M1@TD0 + part1
          float s = wredsum(dotH256(hM1 + (size_t)rg * CD, s_small, lane)) + part1 + b1;
          if (lane == 0) s_gateA[wv] = s;
        }
        if (gi == 2) {                   // rec2(t) row for own element
          float s = wredsum(dotH(hVw2 + (size_t)jown * HD, s_h2, lane)) + vbR2;
          if (lane == 0) s_rec[slot] = s;
        }
        __syncthreads();
        if (tid < 64) {                  // cell3(t) + cell1(t+1) -> publish
          float h3n = 0.f, h1n = 0.f, td1 = 0.f;
          if (lane < 4) {
            {
              float gI = s_gateB[lane * 4 + 0], gF = s_gateB[lane * 4 + 1];
              float gG = s_gateB[lane * 4 + 2], gO = s_gateB[lane * 4 + 3];
              float cn = sigf(gF) * s_c3own[lane] + sigf(gI) * tanhfast(gG);
              h3n = sigf(gO) * tanhfast(cn);
              s_c3own[lane] = cn;
            }
            {
              float gI = s_gateA[lane * 4 + 0], gF = s_gateA[lane * 4 + 1];
              float gG = s_gateA[lane * 4 + 2], gO = s_gateA[lane * 4 + 3];
              float cn = sigf(gF) * s_c1own[lane] + sigf(gI) * tanhfast(gG);
              h1n = sigf(gO) * tanhfast(cn);
              td1 = h1n - s_rec[lane];
              s_c1own[lane] = cn;
            }
          }
          uint2 u3, u1, utd;
          u3.x = packh2(__shfl(h3n, 0), __shfl(h3n, 1)); u3.y = packh2(__shfl(h3n, 2), __shfl(h3n, 3));
          u1.x = packh2(__shfl(h1n, 0), __shfl(h1n, 1)); u1.y = packh2(__shfl(h1n, 2), __shfl(h1n, 3));
          utd.x = packh2(__shfl(td1, 0), __shfl(td1, 1)); utd.y = packh2(__shfl(td1, 2), __shfl(td1, 3));
          if (lane == 0) {
            cstoreU2(d_h3h + bid * 4, u3);
            cstoreU2(d_h1h + bid * 4, u1);
            cstoreU2(d_TD1h + bid * 4, utd);
          }
        }
        // AFTER publish: precompute for P(t+1): W2b@TD2(t)+Whh2@h2(t) (LDS)
        part2 = wredsum(dotH(sW2 + wv * HD, s_TD2, lane)
                      + dotH(sH2 + wv * HD, s_h2,  lane));
        gbar(ep);
      }
    }
  }

  if (iswg0 && tid == 0) { out[0] = loss_acc; out[1] = fll_acc; }
}

extern "C" void kernel_launch(void* const* d_in, const int* in_sizes, int n_in,
                              void* d_out, int out_size, void* d_ws, size_t ws_size,
                              hipStream_t stream) {
  const float* x    = (const float*)d_in[0];
  const float* Wih1 = (const float*)d_in[1];
  const float* Whh1 = (const float*)d_in[2];
  const float* bih1 = (const float*)d_in[3];
  const float* bhh1 = (const float*)d_in[4];
  const float* Vw1  = (const float*)d_in[5];
  const float* Vb1  = (const float*)d_in[6];
  const float* Wih2 = (const float*)d_in[7];
  const float* Whh2 = (const float*)d_in[8];
  const float* bih2 = (const float*)d_in[9];
  const float* bhh2 = (const float*)d_in[10];
  const float* Vw2  = (const float*)d_in[11];
  const float* Vb2  = (const float*)d_in[12];
  const float* Wih3 = (const float*)d_in[13];
  const float* Whh3 = (const float*)d_in[14];
  const float* bih3 = (const float*)d_in[15];
  const float* bhh3 = (const float*)d_in[16];
  const float* Vw3  = (const float*)d_in[17];
  const float* Vb3  = (const float*)d_in[18];
  const float* Ww0  = (const float*)d_in[19];
  const float* Wb0  = (const float*)d_in[20];
  const float* Ww1  = (const float*)d_in[21];
  const float* Wb1  = (const float*)d_in[22];
  const float* Ww2  = (const float*)d_in[23];
  const float* Wb2  = (const float*)d_in[24];
  const float* r1   = (const float*)d_in[25];
  const float* r2   = (const float*)d_in[26];
  const float* r3   = (const float*)d_in[27];

  static int smem_set = 0;
  if (!smem_set) {
    hipFuncSetAttribute((const void*)pc_main,
                        hipFuncAttributeMaxDynamicSharedMemorySize, SMEMB);
    smem_set = 1;
  }

  pc_conv<<<1024, 256, 0, stream>>>(Wih1, Whh1, Wih2, Whh2, Whh3, Vw1, Vw2, Vw3);
  pc_fold<<<2304, 256, 0, stream>>>(Wih1, Wih2, Wih3, Ww0, Ww1, Ww2);
  pc_init<<<1, NWG, 0, stream>>>();
  pc_main<<<NWG, NTH, SMEMB, stream>>>(x, Wih1, Whh1, bih1, bhh1, Vw1, Vb1,
                                       Wih2, Whh2, bih2, bhh2, Vw2, Vb2,
                                       Wih3, Whh3, bih3, bhh3, Vw3, Vb3,
                                       Ww0, Wb0, Ww1, Wb1, Ww2, Wb2,
                                       r1, r2, r3, (float*)d_out);
}